// Round 1
// baseline (824.234 us; speedup 1.0000x reference)
//
#include <hip/hip_runtime.h>
#include <hip/hip_bf16.h>

// dims (fixed per reference)
#define L_   2048
#define H_   2048
#define I_   2048
#define NH_  16
#define HPH_ 128
#define NS_  64
#define R_   128

typedef __attribute__((ext_vector_type(8))) short s16x8;
typedef __attribute__((ext_vector_type(4))) float f32x4;

__device__ __forceinline__ short f2bf(float x) {
  unsigned u = __builtin_bit_cast(unsigned, x);
  u += 0x7fff + ((u >> 16) & 1);   // round-to-nearest-even
  return (short)(u >> 16);
}

// ---- pack weight W[K][N] (f32 row-major) -> Wp[(k>>3)][n][k&7] bf16 ----
__global__ __launch_bounds__(256) void pack_w(const float* __restrict__ W,
                                              short* __restrict__ Wp,
                                              int KN, int logN) {
  int idx = blockIdx.x * 256 + threadIdx.x;
  if (idx >= KN) return;
  int k = idx >> logN;
  int n = idx & ((1 << logN) - 1);
  Wp[((size_t)(k >> 3) << (logN + 3)) + ((size_t)n << 3) + (k & 7)] = f2bf(W[idx]);
}

__global__ __launch_bounds__(256) void cast_bf(const float* __restrict__ X,
                                               short* __restrict__ Xb, int nElem) {
  int idx = blockIdx.x * 256 + threadIdx.x;
  if (idx < nElem) Xb[idx] = f2bf(X[idx]);
}

// ---- bf16 MFMA GEMM: C[M,N] = A[M,K] * B[K,N], A row-major bf16, B packed ----
// block = 256 thr (4 waves, 2x2), block tile 128x128, wave tile 64x64
__global__ __launch_bounds__(256) void gemm_bf16(const short* __restrict__ A,
                                                 const short* __restrict__ Bp,
                                                 float* __restrict__ C,
                                                 int M, int N, int K) {
  int tid = threadIdx.x;
  int lane = tid & 63, wid = tid >> 6;
  int wr = wid >> 1, wc = wid & 1;
  int l15 = lane & 15, l16 = lane >> 4;
  int bm = blockIdx.x * 128, bn = blockIdx.y * 128;

  f32x4 acc[4][4] = {};

  const short* Ab = A + (size_t)(bm + wr * 64 + l15) * K + l16 * 8;
  const short* Bb = Bp + (size_t)l16 * N * 8 + (size_t)(bn + wc * 64 + l15) * 8;

#pragma unroll 2
  for (int k0 = 0; k0 < K; k0 += 32) {
    s16x8 a[4], b[4];
#pragma unroll
    for (int mi = 0; mi < 4; ++mi)
      a[mi] = *(const s16x8*)(Ab + (size_t)mi * 16 * K + k0);
#pragma unroll
    for (int ni = 0; ni < 4; ++ni)
      b[ni] = *(const s16x8*)(Bb + (size_t)k0 * N + ni * 128);
#pragma unroll
    for (int mi = 0; mi < 4; ++mi)
#pragma unroll
      for (int ni = 0; ni < 4; ++ni)
        acc[mi][ni] = __builtin_amdgcn_mfma_f32_16x16x32_bf16(a[mi], b[ni], acc[mi][ni], 0, 0, 0);
  }
  // C/D layout: col = lane&15, row = (lane>>4)*4 + reg  [m89-verified]
#pragma unroll
  for (int mi = 0; mi < 4; ++mi) {
    int row0 = bm + wr * 64 + mi * 16 + l16 * 4;
#pragma unroll
    for (int ni = 0; ni < 4; ++ni) {
      int col = bn + wc * 64 + ni * 16 + l15;
#pragma unroll
      for (int r = 0; r < 4; ++r)
        C[(size_t)(row0 + r) * N + col] = acc[mi][ni][r];
    }
  }
}

// ---- causal depthwise conv (K=4) + SiLU; reads hs half of proj ----
__global__ __launch_bounds__(256) void conv_silu(const float* __restrict__ proj,
                                                 const float* __restrict__ convw,
                                                 float* __restrict__ hs,
                                                 short* __restrict__ hsb) {
  int idx = blockIdx.x * 256 + threadIdx.x;   // over L_*I_
  int t = idx >> 11, i = idx & (I_ - 1);
  int col = ((i >> 7) << 8) + 128 + (i & 127);  // head*256 + 128 + (i%128)
  float4 cw = *(const float4*)(convw + i * 4);
  const float* p = proj + (size_t)t * (2 * I_) + col;
  float acc = cw.w * p[0];
  if (t >= 1) acc += cw.z * p[-(2 * I_)];
  if (t >= 2) acc += cw.y * p[-(2 * I_) * 2];
  if (t >= 3) acc += cw.x * p[-(2 * I_) * 3];
  float h = acc / (1.f + __expf(-acc));   // silu
  hs[idx] = h;
  hsb[idx] = f2bf(h);
}

// ---- RMSNorms (B, C, ts) + dt = ts@dt_proj + softplus(dt + bias) ----
// one wave per token row; block = 4 waves
__global__ __launch_bounds__(256) void norm_dt(const float* __restrict__ sp,    // [L, 2N+R]
                                               const float* __restrict__ Bw,
                                               const float* __restrict__ Cw,
                                               const float* __restrict__ dtw,
                                               const float* __restrict__ Wdt,   // [R, NH]
                                               const float* __restrict__ bias,  // [NH]
                                               float* __restrict__ Bo,
                                               float* __restrict__ Co,
                                               float* __restrict__ delta) {     // [L, NH]
  int lane = threadIdx.x & 63, w = threadIdx.x >> 6;
  int t = blockIdx.x * 4 + w;
  const float* row = sp + (size_t)t * 256;
  float v0 = row[lane], v1 = row[64 + lane], v2 = row[128 + lane], v3 = row[192 + lane];
  float sB = v0 * v0, sC = v1 * v1, sT = v2 * v2 + v3 * v3;
#pragma unroll
  for (int off = 32; off; off >>= 1) {
    sB += __shfl_xor(sB, off);
    sC += __shfl_xor(sC, off);
    sT += __shfl_xor(sT, off);
  }
  float rB = rsqrtf(sB * (1.f / 64) + 1e-6f);
  float rC = rsqrtf(sC * (1.f / 64) + 1e-6f);
  float rT = rsqrtf(sT * (1.f / 128) + 1e-6f);
  Bo[t * 64 + lane] = v0 * rB * Bw[lane];
  Co[t * 64 + lane] = v1 * rC * Cw[lane];
  float t2 = v2 * rT * dtw[lane], t3 = v3 * rT * dtw[64 + lane];
  float p[NH_];
  const float* w0 = Wdt + lane * NH_;
  const float* w1 = Wdt + (64 + lane) * NH_;
#pragma unroll
  for (int h = 0; h < NH_; ++h) p[h] = t2 * w0[h] + t3 * w1[h];
#pragma unroll
  for (int off = 32; off; off >>= 1)
#pragma unroll
    for (int h = 0; h < NH_; ++h) p[h] += __shfl_xor(p[h], off);
  if (lane == 0) {
#pragma unroll
    for (int h = 0; h < NH_; ++h) {
      float x = p[h] + bias[h];
      delta[t * NH_ + h] = (x > 20.f) ? x : log1pf(__expf(x));
    }
  }
}

// ---- selective scan: wave = channel i, lane = state n; fused epilogue ----
#define SCAN_T 64
__global__ __launch_bounds__(512) void scan_k(const float* __restrict__ hs,     // [L, I]
                                              const float* __restrict__ Bm,     // [L, N]
                                              const float* __restrict__ Cm,     // [L, N]
                                              const float* __restrict__ delta,  // [L, NH]
                                              const float* __restrict__ A,      // [I, N]
                                              const float* __restrict__ Dv,     // [I]
                                              const float* __restrict__ proj,   // [L, 2I] (gate)
                                              short* __restrict__ ybf) {        // [L, I] bf16
  __shared__ float sB[SCAN_T][64], sC[SCAN_T][64];
  __shared__ float su[SCAN_T][8], sd[SCAN_T], yb[SCAN_T][8];
  int tid = threadIdx.x;
  int lane = tid & 63, w = tid >> 6;
  int c0 = blockIdx.x * 8;
  int i = c0 + w;
  int head = i >> 7;
  float aPre = A[i * 64 + lane] * 1.4426950408889634f;  // A * log2(e)
  float s = 0.f;

  for (int t0 = 0; t0 < L_; t0 += SCAN_T) {
    __syncthreads();
#pragma unroll
    for (int r = 0; r < 8; ++r) {
      int flat = r * 512 + tid;   // SCAN_T*64 = 4096
      ((float*)sB)[flat] = Bm[t0 * 64 + flat];
      ((float*)sC)[flat] = Cm[t0 * 64 + flat];
    }
    { int tt = tid >> 3, ww = tid & 7;
      su[tt][ww] = hs[(size_t)(t0 + tt) * I_ + c0 + ww]; }
    if (tid < SCAN_T) sd[tid] = delta[(t0 + tid) * NH_ + head];
    __syncthreads();

    for (int tt = 0; tt < SCAN_T; ++tt) {
      float dlt = sd[tt];
      float u = su[tt][w];
      float dA = exp2f(dlt * aPre);
      float x = (dlt * u) * sB[tt][lane];
      s = s * dA + x;
      float pp = s * sC[tt][lane];
#pragma unroll
      for (int off = 32; off; off >>= 1) pp += __shfl_xor(pp, off);
      if (lane == 0) yb[tt][w] = pp;
    }
    __syncthreads();

    // epilogue: y = (ys + D*hs) * silu(gate) -> bf16
    { int tt = tid >> 3, ww = tid & 7;
      int t = t0 + tt, ii = c0 + ww;
      float g = proj[(size_t)t * (2 * I_) + ((ii >> 7) << 8) + (ii & 127)];
      float sg = g / (1.f + __expf(-g));
      float yv = (yb[tt][ww] + Dv[ii] * su[tt][ww]) * sg;
      ybf[(size_t)t * I_ + ii] = f2bf(yv); }
  }
}

extern "C" void kernel_launch(void* const* d_in, const int* in_sizes, int n_in,
                              void* d_out, int out_size, void* d_ws, size_t ws_size,
                              hipStream_t stream) {
  const float* hidden  = (const float*)d_in[0];   // [L, H]
  const float* inproj  = (const float*)d_in[1];   // [H, 2I]
  const float* convw   = (const float*)d_in[2];   // [I, 4]
  const float* bcdtw   = (const float*)d_in[3];   // [I, 2N+R]
  const float* dtnw    = (const float*)d_in[4];   // [R]
  const float* Bnw     = (const float*)d_in[5];   // [N]
  const float* Cnw     = (const float*)d_in[6];   // [N]
  const float* dtpw    = (const float*)d_in[7];   // [R, NH]
  const float* dtbias  = (const float*)d_in[8];   // [NH]
  const float* Amat    = (const float*)d_in[9];   // [I, N]
  const float* Dvec    = (const float*)d_in[10];  // [I]
  const float* outproj = (const float*)d_in[11];  // [I, H]
  float* out = (float*)d_out;

  char* ws = (char*)d_ws;
  short* inproj_p  = (short*)ws; ws += (size_t)H_ * 2 * I_ * 2;   // 16 MB
  short* bcdt_p    = (short*)ws; ws += (size_t)I_ * 256 * 2;      // 1 MB
  short* outproj_p = (short*)ws; ws += (size_t)I_ * H_ * 2;       // 8 MB
  short* hid_b     = (short*)ws; ws += (size_t)L_ * H_ * 2;       // 8 MB
  float* proj      = (float*)ws; ws += (size_t)L_ * 2 * I_ * 4;   // 32 MB
  float* hs        = (float*)ws; ws += (size_t)L_ * I_ * 4;       // 16 MB
  short* hs_b      = (short*)ws; ws += (size_t)L_ * I_ * 2;       // 8 MB
  float* ssmp      = (float*)ws; ws += (size_t)L_ * 256 * 4;      // 2 MB
  float* Bmat      = (float*)ws; ws += (size_t)L_ * NS_ * 4;
  float* Cmat      = (float*)ws; ws += (size_t)L_ * NS_ * 4;
  float* delta     = (float*)ws; ws += (size_t)L_ * NH_ * 4;
  short* y_b       = (short*)ws; ws += (size_t)L_ * I_ * 2;       // 8 MB

  // ---- pack weights / cast activations ----
  pack_w<<<(H_ * 2 * I_ + 255) / 256, 256, 0, stream>>>(inproj, inproj_p, H_ * 2 * I_, 12);
  pack_w<<<(I_ * 256 + 255) / 256, 256, 0, stream>>>(bcdtw, bcdt_p, I_ * 256, 8);
  pack_w<<<(I_ * H_ + 255) / 256, 256, 0, stream>>>(outproj, outproj_p, I_ * H_, 11);
  cast_bf<<<(L_ * H_ + 255) / 256, 256, 0, stream>>>(hidden, hid_b, L_ * H_);

  // ---- 1. in_proj GEMM: [L,H] x [H,2I] ----
  gemm_bf16<<<dim3(L_ / 128, (2 * I_) / 128), 256, 0, stream>>>(hid_b, inproj_p, proj, L_, 2 * I_, H_);

  // ---- 2. conv + silu ----
  conv_silu<<<(L_ * I_) / 256, 256, 0, stream>>>(proj, convw, hs, hs_b);

  // ---- 3. bcdt GEMM: [L,I] x [I,256] ----
  gemm_bf16<<<dim3(L_ / 128, 256 / 128), 256, 0, stream>>>(hs_b, bcdt_p, ssmp, L_, 256, I_);

  // ---- 4. norms + dt projection + softplus ----
  norm_dt<<<L_ / 4, 256, 0, stream>>>(ssmp, Bnw, Cnw, dtnw, dtpw, dtbias, Bmat, Cmat, delta);

  // ---- 5. selective scan (fused D*hs + gate silu epilogue) ----
  scan_k<<<I_ / 8, 512, 0, stream>>>(hs, Bmat, Cmat, delta, Amat, Dvec, proj, y_b);

  // ---- 6. out_proj GEMM: [L,I] x [I,H] ----
  gemm_bf16<<<dim3(L_ / 128, H_ / 128), 256, 0, stream>>>(y_b, outproj_p, out, L_, H_, I_);
}

// Round 2
// 500.093 us; speedup vs baseline: 1.6482x; 1.6482x over previous
//
#include <hip/hip_runtime.h>
#include <hip/hip_bf16.h>

// dims (fixed per reference)
#define L_   2048
#define H_   2048
#define I_   2048
#define NH_  16
#define HPH_ 128
#define NS_  64
#define R_   128

typedef __attribute__((ext_vector_type(8))) short s16x8;
typedef __attribute__((ext_vector_type(4))) float f32x4;

__device__ __forceinline__ short f2bf(float x) {
  unsigned u = __builtin_bit_cast(unsigned, x);
  u += 0x7fff + ((u >> 16) & 1);   // round-to-nearest-even
  return (short)(u >> 16);
}

// ---- pack weight W[K][N] (f32 row-major) -> Wp[(k>>3)][n][k&7] bf16 ----
__global__ __launch_bounds__(256) void pack_w(const float* __restrict__ W,
                                              short* __restrict__ Wp,
                                              int KN, int logN) {
  int idx = blockIdx.x * 256 + threadIdx.x;
  if (idx >= KN) return;
  int k = idx >> logN;
  int n = idx & ((1 << logN) - 1);
  Wp[((size_t)(k >> 3) << (logN + 3)) + ((size_t)n << 3) + (k & 7)] = f2bf(W[idx]);
}

__global__ __launch_bounds__(256) void cast_bf(const float* __restrict__ X,
                                               short* __restrict__ Xb, int nElem) {
  int idx = blockIdx.x * 256 + threadIdx.x;
  if (idx < nElem) Xb[idx] = f2bf(X[idx]);
}

// ---- bf16 MFMA GEMM: C[M,N] = A[M,K] * B[K,N], A row-major bf16, B packed ----
__global__ __launch_bounds__(256) void gemm_bf16(const short* __restrict__ A,
                                                 const short* __restrict__ Bp,
                                                 float* __restrict__ C,
                                                 int M, int N, int K) {
  int tid = threadIdx.x;
  int lane = tid & 63, wid = tid >> 6;
  int wr = wid >> 1, wc = wid & 1;
  int l15 = lane & 15, l16 = lane >> 4;
  int bm = blockIdx.x * 128, bn = blockIdx.y * 128;

  f32x4 acc[4][4] = {};

  const short* Ab = A + (size_t)(bm + wr * 64 + l15) * K + l16 * 8;
  const short* Bb = Bp + (size_t)l16 * N * 8 + (size_t)(bn + wc * 64 + l15) * 8;

#pragma unroll 2
  for (int k0 = 0; k0 < K; k0 += 32) {
    s16x8 a[4], b[4];
#pragma unroll
    for (int mi = 0; mi < 4; ++mi)
      a[mi] = *(const s16x8*)(Ab + (size_t)mi * 16 * K + k0);
#pragma unroll
    for (int ni = 0; ni < 4; ++ni)
      b[ni] = *(const s16x8*)(Bb + (size_t)k0 * N + ni * 128);
#pragma unroll
    for (int mi = 0; mi < 4; ++mi)
#pragma unroll
      for (int ni = 0; ni < 4; ++ni)
        acc[mi][ni] = __builtin_amdgcn_mfma_f32_16x16x32_bf16(a[mi], b[ni], acc[mi][ni], 0, 0, 0);
  }
#pragma unroll
  for (int mi = 0; mi < 4; ++mi) {
    int row0 = bm + wr * 64 + mi * 16 + l16 * 4;
#pragma unroll
    for (int ni = 0; ni < 4; ++ni) {
      int col = bn + wc * 64 + ni * 16 + l15;
#pragma unroll
      for (int r = 0; r < 4; ++r)
        C[(size_t)(row0 + r) * N + col] = acc[mi][ni][r];
    }
  }
}

// ---- causal depthwise conv (K=4) + SiLU; reads hs half of proj ----
__global__ __launch_bounds__(256) void conv_silu(const float* __restrict__ proj,
                                                 const float* __restrict__ convw,
                                                 float* __restrict__ hs,
                                                 short* __restrict__ hsb) {
  int idx = blockIdx.x * 256 + threadIdx.x;   // over L_*I_
  int t = idx >> 11, i = idx & (I_ - 1);
  int col = ((i >> 7) << 8) + 128 + (i & 127);  // head*256 + 128 + (i%128)
  float4 cw = *(const float4*)(convw + i * 4);
  const float* p = proj + (size_t)t * (2 * I_) + col;
  float acc = cw.w * p[0];
  if (t >= 1) acc += cw.z * p[-(2 * I_)];
  if (t >= 2) acc += cw.y * p[-(2 * I_) * 2];
  if (t >= 3) acc += cw.x * p[-(2 * I_) * 3];
  float h = acc / (1.f + __expf(-acc));   // silu
  hs[idx] = h;
  hsb[idx] = f2bf(h);
}

// ---- RMSNorms (B, C, ts) + dt = ts@dt_proj + softplus(dt + bias) ----
__global__ __launch_bounds__(256) void norm_dt(const float* __restrict__ sp,
                                               const float* __restrict__ Bw,
                                               const float* __restrict__ Cw,
                                               const float* __restrict__ dtw,
                                               const float* __restrict__ Wdt,
                                               const float* __restrict__ bias,
                                               float* __restrict__ Bo,
                                               float* __restrict__ Co,
                                               float* __restrict__ delta) {
  int lane = threadIdx.x & 63, w = threadIdx.x >> 6;
  int t = blockIdx.x * 4 + w;
  const float* row = sp + (size_t)t * 256;
  float v0 = row[lane], v1 = row[64 + lane], v2 = row[128 + lane], v3 = row[192 + lane];
  float sB = v0 * v0, sC = v1 * v1, sT = v2 * v2 + v3 * v3;
#pragma unroll
  for (int off = 32; off; off >>= 1) {
    sB += __shfl_xor(sB, off);
    sC += __shfl_xor(sC, off);
    sT += __shfl_xor(sT, off);
  }
  float rB = rsqrtf(sB * (1.f / 64) + 1e-6f);
  float rC = rsqrtf(sC * (1.f / 64) + 1e-6f);
  float rT = rsqrtf(sT * (1.f / 128) + 1e-6f);
  Bo[t * 64 + lane] = v0 * rB * Bw[lane];
  Co[t * 64 + lane] = v1 * rC * Cw[lane];
  float t2 = v2 * rT * dtw[lane], t3 = v3 * rT * dtw[64 + lane];
  float p[NH_];
  const float* w0 = Wdt + lane * NH_;
  const float* w1 = Wdt + (64 + lane) * NH_;
#pragma unroll
  for (int h = 0; h < NH_; ++h) p[h] = t2 * w0[h] + t3 * w1[h];
#pragma unroll
  for (int off = 32; off; off >>= 1)
#pragma unroll
    for (int h = 0; h < NH_; ++h) p[h] += __shfl_xor(p[h], off);
  if (lane == 0) {
#pragma unroll
    for (int h = 0; h < NH_; ++h) {
      float x = p[h] + bias[h];
      delta[t * NH_ + h] = (x > 20.f) ? x : log1pf(__expf(x));
    }
  }
}

// ---- selective scan: wave = channel i, lane = state n; fused epilogue ----
// 8-step batched butterflies + shared-stage reduce + vectorized swizzled LDS.
#define SCAN_T 64
// XOR-swizzled [n][t] index (float4 granule along t, permuted by n&15)
__device__ __forceinline__ int bidx(int n, int t) {
  return n * 64 + ((((t >> 2) ^ (n & 15)) << 2) | (t & 3));
}

__global__ __launch_bounds__(512) void scan_k(const float* __restrict__ hs,     // [L, I]
                                              const float* __restrict__ Bm,     // [L, N]
                                              const float* __restrict__ Cm,     // [L, N]
                                              const float* __restrict__ delta,  // [L, NH]
                                              const float* __restrict__ A,      // [I, N]
                                              const float* __restrict__ Dv,     // [I]
                                              const float* __restrict__ proj,   // [L, 2I] (gate)
                                              short* __restrict__ ybf) {        // [L, I] bf16
  __shared__ float sB[64 * 64], sC[64 * 64];        // swizzled [n][t]
  __shared__ float su_t[8][68], sd_t[68];           // transposed [w][t], [t]
  __shared__ float yb[SCAN_T][9];
  int tid = threadIdx.x;
  int lane = tid & 63, w = tid >> 6;
  int c0 = blockIdx.x * 8;
  int i = c0 + w;
  int head = c0 >> 7;                                // same for all 8 channels in block
  float aPre = A[i * 64 + lane] * 1.4426950408889634f;  // A * log2(e)
  float s = 0.f;
  int ww = tid & 7, tt = tid >> 3;                   // staging/epilogue mapping

  for (int t0 = 0; t0 < L_; t0 += SCAN_T) {
    __syncthreads();
    // stage B/C (float4 loads, swizzled transposed writes)
    const float4* B4 = (const float4*)(Bm + t0 * 64);
    const float4* C4 = (const float4*)(Cm + t0 * 64);
#pragma unroll
    for (int r = 0; r < 2; ++r) {
      int f4 = r * 512 + tid;          // 1024 float4 = 64x64
      float4 bv = B4[f4];
      float4 cv = C4[f4];
      int t = f4 >> 4, n0 = (f4 & 15) << 2;
#pragma unroll
      for (int j = 0; j < 4; ++j) {
        float* pb = &((float*)sB)[bidx(n0 + j, t)];
        float* pc = &((float*)sC)[bidx(n0 + j, t)];
        *pb = (&bv.x)[j];
        *pc = (&cv.x)[j];
      }
    }
    su_t[ww][tt] = hs[(size_t)(t0 + tt) * I_ + c0 + ww];
    if (tid < SCAN_T) sd_t[tid] = delta[(t0 + tid) * NH_ + head];
    __syncthreads();

#pragma unroll 1
    for (int g = 0; g < SCAN_T / 8; ++g) {
      int tg = g * 8;
      // lane-uniform broadcasts
      float4 u_lo = *(const float4*)&su_t[w][tg];
      float4 u_hi = *(const float4*)&su_t[w][tg + 4];
      float4 d_lo = *(const float4*)&sd_t[tg];
      float4 d_hi = *(const float4*)&sd_t[tg + 4];
      // per-lane B/C for 8 steps (swizzled b128 x2 each)
      float4 b_lo = *(const float4*)&sB[bidx(lane, tg)];
      float4 b_hi = *(const float4*)&sB[bidx(lane, tg + 4)];
      float4 c_lo = *(const float4*)&sC[bidx(lane, tg)];
      float4 c_hi = *(const float4*)&sC[bidx(lane, tg + 4)];

      float pp[8];
#pragma unroll
      for (int j = 0; j < 8; ++j) {
        float dlt = (j < 4) ? (&d_lo.x)[j] : (&d_hi.x)[j - 4];
        float uu  = (j < 4) ? (&u_lo.x)[j] : (&u_hi.x)[j - 4];
        float bb  = (j < 4) ? (&b_lo.x)[j] : (&b_hi.x)[j - 4];
        float cc  = (j < 4) ? (&c_lo.x)[j] : (&c_hi.x)[j - 4];
        float dA = exp2f(dlt * aPre);
        s = s * dA + (dlt * uu) * bb;
        pp[j] = s * cc;
      }
      // shared-stage reduce: stages {8,16,32} on all 8 (ILP), select, {1,2,4}
#pragma unroll
      for (int j = 0; j < 8; ++j) pp[j] += __shfl_xor(pp[j], 8);
#pragma unroll
      for (int j = 0; j < 8; ++j) pp[j] += __shfl_xor(pp[j], 16);
#pragma unroll
      for (int j = 0; j < 8; ++j) pp[j] += __shfl_xor(pp[j], 32);
      // select value (lane>>3)&7 -> this 8-lane group reduces that value
      bool b3 = lane & 8, b4 = lane & 16, b5 = lane & 32;
      float w01 = b3 ? pp[1] : pp[0], w23 = b3 ? pp[3] : pp[2];
      float w45 = b3 ? pp[5] : pp[4], w67 = b3 ? pp[7] : pp[6];
      float w03 = b4 ? w23 : w01, w47 = b4 ? w67 : w45;
      float wv  = b5 ? w47 : w03;
      wv += __shfl_xor(wv, 1);
      wv += __shfl_xor(wv, 2);
      wv += __shfl_xor(wv, 4);
      if ((lane & 7) == 0) yb[tg + (lane >> 3)][w] = wv;
    }
    __syncthreads();

    // epilogue: y = (ys + D*hs) * silu(gate) -> bf16
    {
      int t = t0 + tt, ii = c0 + ww;
      float g = proj[(size_t)t * (2 * I_) + ((ii >> 7) << 8) + (ii & 127)];
      float sg = g / (1.f + __expf(-g));
      float yv = (yb[tt][ww] + Dv[ii] * su_t[ww][tt]) * sg;
      ybf[(size_t)t * I_ + ii] = f2bf(yv);
    }
  }
}

extern "C" void kernel_launch(void* const* d_in, const int* in_sizes, int n_in,
                              void* d_out, int out_size, void* d_ws, size_t ws_size,
                              hipStream_t stream) {
  const float* hidden  = (const float*)d_in[0];
  const float* inproj  = (const float*)d_in[1];
  const float* convw   = (const float*)d_in[2];
  const float* bcdtw   = (const float*)d_in[3];
  const float* dtnw    = (const float*)d_in[4];
  const float* Bnw     = (const float*)d_in[5];
  const float* Cnw     = (const float*)d_in[6];
  const float* dtpw    = (const float*)d_in[7];
  const float* dtbias  = (const float*)d_in[8];
  const float* Amat    = (const float*)d_in[9];
  const float* Dvec    = (const float*)d_in[10];
  const float* outproj = (const float*)d_in[11];
  float* out = (float*)d_out;

  char* ws = (char*)d_ws;
  short* inproj_p  = (short*)ws; ws += (size_t)H_ * 2 * I_ * 2;
  short* bcdt_p    = (short*)ws; ws += (size_t)I_ * 256 * 2;
  short* outproj_p = (short*)ws; ws += (size_t)I_ * H_ * 2;
  short* hid_b     = (short*)ws; ws += (size_t)L_ * H_ * 2;
  float* proj      = (float*)ws; ws += (size_t)L_ * 2 * I_ * 4;
  float* hs        = (float*)ws; ws += (size_t)L_ * I_ * 4;
  short* hs_b      = (short*)ws; ws += (size_t)L_ * I_ * 2;
  float* ssmp      = (float*)ws; ws += (size_t)L_ * 256 * 4;
  float* Bmat      = (float*)ws; ws += (size_t)L_ * NS_ * 4;
  float* Cmat      = (float*)ws; ws += (size_t)L_ * NS_ * 4;
  float* delta     = (float*)ws; ws += (size_t)L_ * NH_ * 4;
  short* y_b       = (short*)ws; ws += (size_t)L_ * I_ * 2;

  pack_w<<<(H_ * 2 * I_ + 255) / 256, 256, 0, stream>>>(inproj, inproj_p, H_ * 2 * I_, 12);
  pack_w<<<(I_ * 256 + 255) / 256, 256, 0, stream>>>(bcdtw, bcdt_p, I_ * 256, 8);
  pack_w<<<(I_ * H_ + 255) / 256, 256, 0, stream>>>(outproj, outproj_p, I_ * H_, 11);
  cast_bf<<<(L_ * H_ + 255) / 256, 256, 0, stream>>>(hidden, hid_b, L_ * H_);

  gemm_bf16<<<dim3(L_ / 128, (2 * I_) / 128), 256, 0, stream>>>(hid_b, inproj_p, proj, L_, 2 * I_, H_);
  conv_silu<<<(L_ * I_) / 256, 256, 0, stream>>>(proj, convw, hs, hs_b);
  gemm_bf16<<<dim3(L_ / 128, 256 / 128), 256, 0, stream>>>(hs_b, bcdt_p, ssmp, L_, 256, I_);
  norm_dt<<<L_ / 4, 256, 0, stream>>>(ssmp, Bnw, Cnw, dtnw, dtpw, dtbias, Bmat, Cmat, delta);
  scan_k<<<I_ / 8, 512, 0, stream>>>(hs, Bmat, Cmat, delta, Amat, Dvec, proj, y_b);
  gemm_bf16<<<dim3(L_ / 128, H_ / 128), 256, 0, stream>>>(y_b, outproj_p, out, L_, H_, I_);
}

// Round 5
// 487.416 us; speedup vs baseline: 1.6910x; 1.0260x over previous
//
#include <hip/hip_runtime.h>
#include <hip/hip_bf16.h>

// dims (fixed per reference)
#define L_   2048
#define H_   2048
#define I_   2048
#define NH_  16
#define HPH_ 128
#define NS_  64
#define R_   128

typedef __attribute__((ext_vector_type(8))) short s16x8;
typedef __attribute__((ext_vector_type(4))) float f32x4;

__device__ __forceinline__ short f2bf(float x) {
  unsigned u = __builtin_bit_cast(unsigned, x);
  u += 0x7fff + ((u >> 16) & 1);   // round-to-nearest-even
  return (short)(u >> 16);
}

// ---- pack weight W[K][N] (f32 row-major) -> Wp[(k>>3)][n][k&7] bf16 ----
__global__ __launch_bounds__(256) void pack_w(const float* __restrict__ W,
                                              short* __restrict__ Wp,
                                              int KN, int logN) {
  int idx = blockIdx.x * 256 + threadIdx.x;
  if (idx >= KN) return;
  int k = idx >> logN;
  int n = idx & ((1 << logN) - 1);
  Wp[((size_t)(k >> 3) << (logN + 3)) + ((size_t)n << 3) + (k & 7)] = f2bf(W[idx]);
}

__global__ __launch_bounds__(256) void cast_bf(const float* __restrict__ X,
                                               short* __restrict__ Xb, int nElem) {
  int idx = blockIdx.x * 256 + threadIdx.x;
  if (idx < nElem) Xb[idx] = f2bf(X[idx]);
}

// ---- bf16 MFMA GEMM: C[M,N] = A[M,K] * B[K,N], A row-major bf16, B packed ----
__global__ __launch_bounds__(256) void gemm_bf16(const short* __restrict__ A,
                                                 const short* __restrict__ Bp,
                                                 float* __restrict__ C,
                                                 int M, int N, int K) {
  int tid = threadIdx.x;
  int lane = tid & 63, wid = tid >> 6;
  int wr = wid >> 1, wc = wid & 1;
  int l15 = lane & 15, l16 = lane >> 4;
  int bm = blockIdx.x * 128, bn = blockIdx.y * 128;

  f32x4 acc[4][4] = {};

  const short* Ab = A + (size_t)(bm + wr * 64 + l15) * K + l16 * 8;
  const short* Bb = Bp + (size_t)l16 * N * 8 + (size_t)(bn + wc * 64 + l15) * 8;

#pragma unroll 2
  for (int k0 = 0; k0 < K; k0 += 32) {
    s16x8 a[4], b[4];
#pragma unroll
    for (int mi = 0; mi < 4; ++mi)
      a[mi] = *(const s16x8*)(Ab + (size_t)mi * 16 * K + k0);
#pragma unroll
    for (int ni = 0; ni < 4; ++ni)
      b[ni] = *(const s16x8*)(Bb + (size_t)k0 * N + ni * 128);
#pragma unroll
    for (int mi = 0; mi < 4; ++mi)
#pragma unroll
      for (int ni = 0; ni < 4; ++ni)
        acc[mi][ni] = __builtin_amdgcn_mfma_f32_16x16x32_bf16(a[mi], b[ni], acc[mi][ni], 0, 0, 0);
  }
#pragma unroll
  for (int mi = 0; mi < 4; ++mi) {
    int row0 = bm + wr * 64 + mi * 16 + l16 * 4;
#pragma unroll
    for (int ni = 0; ni < 4; ++ni) {
      int col = bn + wc * 64 + ni * 16 + l15;
#pragma unroll
      for (int r = 0; r < 4; ++r)
        C[(size_t)(row0 + r) * N + col] = acc[mi][ni][r];
    }
  }
}

// ---- causal depthwise conv (K=4) + SiLU; reads hs half of proj ----
__global__ __launch_bounds__(256) void conv_silu(const float* __restrict__ proj,
                                                 const float* __restrict__ convw,
                                                 float* __restrict__ hs,
                                                 short* __restrict__ hsb) {
  int idx = blockIdx.x * 256 + threadIdx.x;   // over L_*I_
  int t = idx >> 11, i = idx & (I_ - 1);
  int col = ((i >> 7) << 8) + 128 + (i & 127);  // head*256 + 128 + (i%128)
  float4 cw = *(const float4*)(convw + i * 4);
  const float* p = proj + (size_t)t * (2 * I_) + col;
  float acc = cw.w * p[0];
  if (t >= 1) acc += cw.z * p[-(2 * I_)];
  if (t >= 2) acc += cw.y * p[-(2 * I_) * 2];
  if (t >= 3) acc += cw.x * p[-(2 * I_) * 3];
  float h = acc / (1.f + __expf(-acc));   // silu
  hs[idx] = h;
  hsb[idx] = f2bf(h);
}

// ---- RMSNorms (B, C, ts) + dt = ts@dt_proj + softplus(dt + bias) ----
__global__ __launch_bounds__(256) void norm_dt(const float* __restrict__ sp,
                                               const float* __restrict__ Bw,
                                               const float* __restrict__ Cw,
                                               const float* __restrict__ dtw,
                                               const float* __restrict__ Wdt,
                                               const float* __restrict__ bias,
                                               float* __restrict__ Bo,
                                               float* __restrict__ Co,
                                               float* __restrict__ delta) {
  int lane = threadIdx.x & 63, w = threadIdx.x >> 6;
  int t = blockIdx.x * 4 + w;
  const float* row = sp + (size_t)t * 256;
  float v0 = row[lane], v1 = row[64 + lane], v2 = row[128 + lane], v3 = row[192 + lane];
  float sB = v0 * v0, sC = v1 * v1, sT = v2 * v2 + v3 * v3;
#pragma unroll
  for (int off = 32; off; off >>= 1) {
    sB += __shfl_xor(sB, off);
    sC += __shfl_xor(sC, off);
    sT += __shfl_xor(sT, off);
  }
  float rB = rsqrtf(sB * (1.f / 64) + 1e-6f);
  float rC = rsqrtf(sC * (1.f / 64) + 1e-6f);
  float rT = rsqrtf(sT * (1.f / 128) + 1e-6f);
  Bo[t * 64 + lane] = v0 * rB * Bw[lane];
  Co[t * 64 + lane] = v1 * rC * Cw[lane];
  float t2 = v2 * rT * dtw[lane], t3 = v3 * rT * dtw[64 + lane];
  float p[NH_];
  const float* w0 = Wdt + lane * NH_;
  const float* w1 = Wdt + (64 + lane) * NH_;
#pragma unroll
  for (int h = 0; h < NH_; ++h) p[h] = t2 * w0[h] + t3 * w1[h];
#pragma unroll
  for (int off = 32; off; off >>= 1)
#pragma unroll
    for (int h = 0; h < NH_; ++h) p[h] += __shfl_xor(p[h], off);
  if (lane == 0) {
#pragma unroll
    for (int h = 0; h < NH_; ++h) {
      float x = p[h] + bias[h];
      delta[t * NH_ + h] = (x > 20.f) ? x : log1pf(__expf(x));
    }
  }
}

// ======================= selective scan =======================
// wave = channel i, lane = state n. Proven primitives only:
// __shfl_xor folds + cndmask selects (round-2-verified scheme, restructured
// as interleaved fold-select tree: 17 shfl per 8 steps instead of 27),
// u/delta broadcast via v_readlane, B/C via swizzled ds_read_b128.

__device__ __forceinline__ float rdlane(float v, int l) {
  return __builtin_bit_cast(float, __builtin_amdgcn_readlane(__builtin_bit_cast(int, v), l));
}

#define SCAN_T 64
// XOR-swizzled [n][t] index (float4 granule along t, permuted by n&15)
__device__ __forceinline__ int bidx(int n, int t) {
  return n * 64 + ((((t >> 2) ^ (n & 15)) << 2) | (t & 3));
}

__global__ __launch_bounds__(512) void scan_k(const float* __restrict__ hs,     // [L, I]
                                              const float* __restrict__ Bm,     // [L, N]
                                              const float* __restrict__ Cm,     // [L, N]
                                              const float* __restrict__ delta,  // [L, NH]
                                              const float* __restrict__ A,      // [I, N]
                                              const float* __restrict__ Dv,     // [I]
                                              const float* __restrict__ proj,   // [L, 2I] (gate)
                                              short* __restrict__ ybf) {        // [L, I] bf16
  __shared__ float sBC[2][64 * 64];                 // swizzled [n][t], B then C
  __shared__ float su_t[8][68], sd_t[64];           // transposed [w][t], [t]
  __shared__ float yb[SCAN_T][9];
  int tid = threadIdx.x;
  int lane = tid & 63, w = tid >> 6;
  int c0 = blockIdx.x * 8;
  int i = c0 + w;
  int head = c0 >> 7;
  float aPre = A[i * 64 + lane] * 1.4426950408889634f;  // A * log2(e)
  float s = 0.f;
  int ww = tid & 7, tt = tid >> 3;                   // staging/epilogue mapping
  int l15 = lane & 15;
  int ldsbase = lane << 6;                           // lane*64 floats

  for (int t0 = 0; t0 < L_; t0 += SCAN_T) {
    __syncthreads();
    // stage B/C (float4 global loads, swizzled transposed LDS writes)
    const float4* B4 = (const float4*)(Bm + t0 * 64);
    const float4* C4 = (const float4*)(Cm + t0 * 64);
#pragma unroll
    for (int r = 0; r < 2; ++r) {
      int f4 = r * 512 + tid;          // 1024 float4 = 64x64
      float4 bv = B4[f4];
      float4 cv = C4[f4];
      int t = f4 >> 4, n0 = (f4 & 15) << 2;
#pragma unroll
      for (int j = 0; j < 4; ++j) {
        sBC[0][bidx(n0 + j, t)] = (&bv.x)[j];
        sBC[1][bidx(n0 + j, t)] = (&cv.x)[j];
      }
    }
    su_t[ww][tt] = hs[(size_t)(t0 + tt) * I_ + c0 + ww];
    if (tid < SCAN_T) sd_t[tid] = delta[(t0 + tid) * NH_ + head];
    __syncthreads();

    // per-lane registers: lane l holds u[t0+l], d[t0+l]
    float u_r = su_t[w][lane];
    float d_r = sd_t[lane];

#pragma unroll 1
    for (int g = 0; g < 8; ++g) {
      int tg = g * 8;
      // uniform scalars via readlane (no LDS traffic)
      float dsj[8], usj[8];
#pragma unroll
      for (int j = 0; j < 8; ++j) {
        dsj[j] = rdlane(d_r, tg + j);
        usj[j] = rdlane(u_r, tg + j);
      }
      // per-lane B/C for 8 steps (2x ds_read_b128 each)
      int g2 = tg >> 2;
      int off_lo = ldsbase + ((g2 ^ l15) << 2);
      int off_hi = ldsbase + (((g2 + 1) ^ l15) << 2);
      float4 b_lo = *(const float4*)&sBC[0][off_lo];
      float4 b_hi = *(const float4*)&sBC[0][off_hi];
      float4 c_lo = *(const float4*)&sBC[1][off_lo];
      float4 c_hi = *(const float4*)&sBC[1][off_hi];

      float dA[8], xx[8];
#pragma unroll
      for (int j = 0; j < 8; ++j) {
        float bb = (j < 4) ? (&b_lo.x)[j] : (&b_hi.x)[j - 4];
        dA[j] = exp2f(dsj[j] * aPre);
        xx[j] = (dsj[j] * usj[j]) * bb;
      }
      float pp[8];
#pragma unroll
      for (int j = 0; j < 8; ++j) {
        s = s * dA[j] + xx[j];
        float cc = (j < 4) ? (&c_lo.x)[j] : (&c_hi.x)[j - 4];
        pp[j] = s * cc;
      }
      // interleaved fold-select tree (17 shfl), proven primitives only.
      // After each fold the value is independent of the folded bit, so the
      // following cndmask select is well-defined.  Final value at lane 8j
      // is value j = 4*b5 + 2*b4 + b3 summed over all 64 lanes.
      bool b3 = lane & 8, b4 = lane & 16, b5 = lane & 32;
#pragma unroll
      for (int j = 0; j < 8; ++j) pp[j] += __shfl_xor(pp[j], 8);
      float q0 = b3 ? pp[1] : pp[0];        // value 0+b3
      float q1 = b3 ? pp[3] : pp[2];        // value 2+b3
      float q2 = b3 ? pp[5] : pp[4];        // value 4+b3
      float q3 = b3 ? pp[7] : pp[6];        // value 6+b3
      q0 += __shfl_xor(q0, 16);
      q1 += __shfl_xor(q1, 16);
      q2 += __shfl_xor(q2, 16);
      q3 += __shfl_xor(q3, 16);
      float r0 = b4 ? q1 : q0;              // value 2*b4+b3
      float r1 = b4 ? q3 : q2;              // value 4+2*b4+b3
      r0 += __shfl_xor(r0, 32);
      r1 += __shfl_xor(r1, 32);
      float wv = b5 ? r1 : r0;              // value 4*b5+2*b4+b3
      wv += __shfl_xor(wv, 1);
      wv += __shfl_xor(wv, 2);
      wv += __shfl_xor(wv, 4);
      if ((lane & 7) == 0) yb[tg + (lane >> 3)][w] = wv;
    }
    __syncthreads();

    // epilogue: y = (ys + D*hs) * silu(gate) -> bf16
    {
      int t = t0 + tt, ii = c0 + ww;
      float g = proj[(size_t)t * (2 * I_) + ((ii >> 7) << 8) + (ii & 127)];
      float sg = g / (1.f + __expf(-g));
      float yv = (yb[tt][ww] + Dv[ii] * su_t[ww][tt]) * sg;
      ybf[(size_t)t * I_ + ii] = f2bf(yv);
    }
  }
}

extern "C" void kernel_launch(void* const* d_in, const int* in_sizes, int n_in,
                              void* d_out, int out_size, void* d_ws, size_t ws_size,
                              hipStream_t stream) {
  const float* hidden  = (const float*)d_in[0];
  const float* inproj  = (const float*)d_in[1];
  const float* convw   = (const float*)d_in[2];
  const float* bcdtw   = (const float*)d_in[3];
  const float* dtnw    = (const float*)d_in[4];
  const float* Bnw     = (const float*)d_in[5];
  const float* Cnw     = (const float*)d_in[6];
  const float* dtpw    = (const float*)d_in[7];
  const float* dtbias  = (const float*)d_in[8];
  const float* Amat    = (const float*)d_in[9];
  const float* Dvec    = (const float*)d_in[10];
  const float* outproj = (const float*)d_in[11];
  float* out = (float*)d_out;

  char* ws = (char*)d_ws;
  short* inproj_p  = (short*)ws; ws += (size_t)H_ * 2 * I_ * 2;
  short* bcdt_p    = (short*)ws; ws += (size_t)I_ * 256 * 2;
  short* outproj_p = (short*)ws; ws += (size_t)I_ * H_ * 2;
  short* hid_b     = (short*)ws; ws += (size_t)L_ * H_ * 2;
  float* proj      = (float*)ws; ws += (size_t)L_ * 2 * I_ * 4;
  float* hs        = (float*)ws; ws += (size_t)L_ * I_ * 4;
  short* hs_b      = (short*)ws; ws += (size_t)L_ * I_ * 2;
  float* ssmp      = (float*)ws; ws += (size_t)L_ * 256 * 4;
  float* Bmat      = (float*)ws; ws += (size_t)L_ * NS_ * 4;
  float* Cmat      = (float*)ws; ws += (size_t)L_ * NS_ * 4;
  float* delta     = (float*)ws; ws += (size_t)L_ * NH_ * 4;
  short* y_b       = (short*)ws; ws += (size_t)L_ * I_ * 2;

  pack_w<<<(H_ * 2 * I_ + 255) / 256, 256, 0, stream>>>(inproj, inproj_p, H_ * 2 * I_, 12);
  pack_w<<<(I_ * 256 + 255) / 256, 256, 0, stream>>>(bcdtw, bcdt_p, I_ * 256, 8);
  pack_w<<<(I_ * H_ + 255) / 256, 256, 0, stream>>>(outproj, outproj_p, I_ * H_, 11);
  cast_bf<<<(L_ * H_ + 255) / 256, 256, 0, stream>>>(hidden, hid_b, L_ * H_);

  gemm_bf16<<<dim3(L_ / 128, (2 * I_) / 128), 256, 0, stream>>>(hid_b, inproj_p, proj, L_, 2 * I_, H_);
  conv_silu<<<(L_ * I_) / 256, 256, 0, stream>>>(proj, convw, hs, hs_b);
  gemm_bf16<<<dim3(L_ / 128, 256 / 128), 256, 0, stream>>>(hs_b, bcdt_p, ssmp, L_, 256, I_);
  norm_dt<<<L_ / 4, 256, 0, stream>>>(ssmp, Bnw, Cnw, dtnw, dtpw, dtbias, Bmat, Cmat, delta);
  scan_k<<<I_ / 8, 512, 0, stream>>>(hs, Bmat, Cmat, delta, Amat, Dvec, proj, y_b);
  gemm_bf16<<<dim3(L_ / 128, H_ / 128), 256, 0, stream>>>(y_b, outproj_p, out, L_, H_, I_);
}